// Round 6
// baseline (508.136 us; speedup 1.0000x reference)
//
#include <hip/hip_runtime.h>
#include <hip/hip_bf16.h>
#include <stdint.h>

#define B_SZ   128
#define D_SZ   3072
#define N_SZ   20000
#define NPAD   20480   // 313*64 score tiles (20032) < NPAD; 40 drift K-chunks * 512
#define BN     (B_SZ * NPAD)     // 2621440 elems
#define BD     (B_SZ * D_SZ)     // 393216 elems

typedef __attribute__((ext_vector_type(8))) short        short8;
typedef __attribute__((ext_vector_type(4))) float        f32x4;
typedef __attribute__((ext_vector_type(2))) unsigned int uint2v;

__device__ __forceinline__ unsigned short f2bf(float f) {
    unsigned u = __float_as_uint(f);
    u += 0x7FFFu + ((u >> 16) & 1u);   // round-to-nearest-even
    return (unsigned short)(u >> 16);
}
__device__ __forceinline__ float bf2f(unsigned short h) {
    return __uint_as_float(((unsigned)h) << 16);
}
// order-preserving float<->uint key for atomicMax over signed floats
__device__ __forceinline__ unsigned fkey_enc(float f) {
    unsigned b = __float_as_uint(f);
    return (b & 0x80000000u) ? ~b : (b | 0x80000000u);
}
__device__ __forceinline__ float fkey_dec(unsigned u) {
    return __uint_as_float((u & 0x80000000u) ? (u ^ 0x80000000u) : ~u);
}

__device__ __forceinline__ void gl_lds16(const void* g, void* l) {
    __builtin_amdgcn_global_load_lds(
        (const __attribute__((address_space(1))) void*)g,
        (__attribute__((address_space(3))) void*)l, 16, 0, 0);
}

// bank swizzle: 16B slot for (row r, k-quarter q) is q ^ ((r>>1)&3) -> 2-way
// aliasing only (free, m136); permutes within a 64B row so global coalescing
// of the staging loads is unchanged.
__device__ __forceinline__ int swz(int r, int q) { return q ^ ((r >> 1) & 3); }

// ---------------- zero G2 + Mkey + L (20736 floats, contiguous) ------------
__global__ __launch_bounds__(256) void zero_small(float* __restrict__ p)
{
    p[blockIdx.x * 256 + threadIdx.x] = 0.f;   // grid 81: 81*256 = 20736
}

// ---------------- split x into bf16 hi/lo ----------------
__global__ __launch_bounds__(256) void prep_x(const float* __restrict__ x,
                                              unsigned short* __restrict__ xhi,
                                              unsigned short* __restrict__ xlo)
{
    int i = blockIdx.x * 256 + threadIdx.x;     // exactly 128*3072
    float v = x[i];
    unsigned short h = f2bf(v);
    xhi[i] = h;
    xlo[i] = f2bf(v - bf2f(h));
}

// ---------------- scores: XG_part[kc][b][n] = partial x.g (plain stores) ----
// grid = 313 n-tiles * 8 K-chunks = 2504 blocks. Tile M=128 x N=64, K 384.
// ONE barrier per 32-K step: double-buffered LDS; gl_lds + global G loads for
// step s+1 issued before the MFMA phase of step s; convert+ds_write after.
// split-precision: acc = xhi*ghi + xhi*glo + xlo*ghi (fp32-accurate dot)
__global__ __launch_bounds__(256) void scores_kernel(
        const float* __restrict__ gt,
        const unsigned short* __restrict__ xhi,
        const unsigned short* __restrict__ xlo,
        float* __restrict__ XG_part,
        float* __restrict__ G2)
{
    __shared__ __align__(16) unsigned short Xhi_t[2 * 128 * 32];   // 16 KB
    __shared__ __align__(16) unsigned short Xlo_t[2 * 128 * 32];   // 16 KB
    __shared__ __align__(16) unsigned short Ghi_t[2 * 64 * 32];    //  8 KB
    __shared__ __align__(16) unsigned short Glo_t[2 * 64 * 32];    //  8 KB

    const int tid   = threadIdx.x;
    const int kc    = blockIdx.x & 7;        // K-chunk (8 x 384)
    const int nt    = blockIdx.x >> 3;       // n-tile (313)
    const int nbase = nt * 64;
    const int kcb   = kc * 384;

    const int lane = tid & 63;
    const int wave = tid >> 6;
    const int mh = wave & 1;      // M half (64 rows)
    const int nh = wave >> 1;     // N half (32 cols)
    const int lm = lane & 15;
    const int qd = lane >> 4;

    // G staging map: thread -> (row gn of 64, k-quarter gq of 4 -> 8 elems)
    const int gn = tid >> 2;
    const int gq = tid & 3;
    const int ng0 = nbase + gn;              // unclamped (for guards)
    int grow = ng0 > N_SZ - 1 ? N_SZ - 1 : ng0;
    const float* gp0 = gt + (size_t)grow * D_SZ + kcb + gq * 8;
    const int gwr = gn * 32 + swz(gn, gq) * 8;   // swizzled LDS slot (elems)

    // X staging (global_load_lds, lane-order dest, swizzled source)
    int xsrc[2], xdst[2];
    #pragma unroll
    for (int i = 0; i < 2; i++) {
        int o = (i * 256 + tid) * 16;
        int r = o >> 6;
        int j = (o >> 4) & 3;
        xdst[i] = o;                               // bytes within one buffer
        xsrc[i] = r * D_SZ + kcb + swz(r, j) * 8;  // elems
    }

    float g2acc = 0.0f;

    f32x4 acc[4][2];
    #pragma unroll
    for (int i = 0; i < 4; i++)
        #pragma unroll
        for (int j = 0; j < 2; j++)
            acc[i][j] = (f32x4){0.f, 0.f, 0.f, 0.f};

    // ---- prologue: stage step 0 into buffer 0 ----
    {
        #pragma unroll
        for (int i = 0; i < 2; i++) {
            gl_lds16(xhi + xsrc[i], (char*)Xhi_t + xdst[i]);
            gl_lds16(xlo + xsrc[i], (char*)Xlo_t + xdst[i]);
        }
        f32x4 v0 = *(const f32x4*)(gp0);
        f32x4 v1 = *(const f32x4*)(gp0 + 4);
        short8 h8, l8;
        #pragma unroll
        for (int j = 0; j < 4; j++) {
            float a = v0[j], b = v1[j];
            unsigned short ha = f2bf(a), hb = f2bf(b);
            h8[j]     = (short)ha;  h8[j + 4] = (short)hb;
            l8[j]     = (short)f2bf(a - bf2f(ha));
            l8[j + 4] = (short)f2bf(b - bf2f(hb));
            g2acc += a * a + b * b;
        }
        *(short8*)&Ghi_t[gwr] = h8;
        *(short8*)&Glo_t[gwr] = l8;
        __syncthreads();
    }

    // ---- main loop: one barrier per step ----
    for (int s = 0; s < 12; s++) {
        const int cur = s & 1;
        const int nxt = cur ^ 1;

        f32x4 v0, v1;
        if (s < 11) {
            const int kn = (s + 1) * 32;
            // async global->LDS prefetch of X step s+1 into buf nxt
            #pragma unroll
            for (int i = 0; i < 2; i++) {
                gl_lds16(xhi + xsrc[i] + kn, (char*)Xhi_t + nxt * 8192 + xdst[i]);
                gl_lds16(xlo + xsrc[i] + kn, (char*)Xlo_t + nxt * 8192 + xdst[i]);
            }
            // G global loads for step s+1 (consumed after MFMA phase)
            v0 = *(const f32x4*)(gp0 + kn);
            v1 = *(const f32x4*)(gp0 + kn + 4);
        }

        // MFMA phase on buffer cur
        {
            const int xb = cur * 4096;   // elems per X buffer
            const int gb = cur * 2048;   // elems per G buffer
            short8 bhi[2], blo[2];
            #pragma unroll
            for (int ni = 0; ni < 2; ni++) {
                int r = nh * 32 + ni * 16 + lm;
                int sl = gb + r * 32 + swz(r, qd) * 8;
                bhi[ni] = *(short8*)&Ghi_t[sl];
                blo[ni] = *(short8*)&Glo_t[sl];
            }
            #pragma unroll
            for (int mi = 0; mi < 4; mi++) {
                int r = mh * 64 + mi * 16 + lm;
                int sl = xb + r * 32 + swz(r, qd) * 8;
                short8 ahi = *(short8*)&Xhi_t[sl];
                short8 alo = *(short8*)&Xlo_t[sl];
                #pragma unroll
                for (int ni = 0; ni < 2; ni++) {
                    acc[mi][ni] = __builtin_amdgcn_mfma_f32_16x16x32_bf16(ahi, bhi[ni], acc[mi][ni], 0, 0, 0);
                    acc[mi][ni] = __builtin_amdgcn_mfma_f32_16x16x32_bf16(ahi, blo[ni], acc[mi][ni], 0, 0, 0);
                    acc[mi][ni] = __builtin_amdgcn_mfma_f32_16x16x32_bf16(alo, bhi[ni], acc[mi][ni], 0, 0, 0);
                }
            }
        }

        // convert + stage G step s+1 into buf nxt
        if (s < 11) {
            short8 h8, l8;
            #pragma unroll
            for (int j = 0; j < 4; j++) {
                float a = v0[j], b = v1[j];
                unsigned short ha = f2bf(a), hb = f2bf(b);
                h8[j]     = (short)ha;  h8[j + 4] = (short)hb;
                l8[j]     = (short)f2bf(a - bf2f(ha));
                l8[j + 4] = (short)f2bf(b - bf2f(hb));
                g2acc += a * a + b * b;
            }
            *(short8*)&Ghi_t[nxt * 2048 + gwr] = h8;
            *(short8*)&Glo_t[nxt * 2048 + gwr] = l8;
        }
        __syncthreads();
    }

    // g2 partial: reduce over the 4 k-quarter threads of each row, one atomic
    g2acc += __shfl_xor(g2acc, 1);
    g2acc += __shfl_xor(g2acc, 2);
    if (gq == 0 && ng0 < N_SZ) atomicAdd(&G2[ng0], g2acc);

    // epilogue: C/D layout col=lane&15, row=qd*4+i ; plain store of partial
    float* XGp = XG_part + (size_t)kc * BN;
    #pragma unroll
    for (int mi = 0; mi < 4; mi++) {
        #pragma unroll
        for (int ni = 0; ni < 2; ni++) {
            int ncol = nh * 32 + ni * 16 + lm;
            int ng = nbase + ncol;
            if (ng < N_SZ) {
                #pragma unroll
                for (int i = 0; i < 4; i++) {
                    int m = mh * 64 + mi * 16 + qd * 4 + i;
                    XGp[(size_t)m * NPAD + ng] = acc[mi][ni][i];
                }
            }
        }
    }
}

// ---------------- maxk: XG = sum_kc XG_part; row max of c1*xg - c2*g2 ------
__global__ __launch_bounds__(256) void maxk(
        const float* __restrict__ XG_part, const float* __restrict__ G2,
        const float* __restrict__ tarr, unsigned* __restrict__ Mkey,
        float* __restrict__ XG)
{
    const int b  = blockIdx.x >> 3;
    const int ch = blockIdx.x & 7;
    const int tid = threadIdx.x;
    float tt  = tarr[b] / 999.0f;
    float sig = 1.0f - tt;
    float inv = 1.0f / (sig * sig);
    float c1 = tt * inv, c2 = 0.5f * tt * tt * inv;
    __shared__ float wred[4];

    float mx = -3.402823466e+38f;
    int n0 = ch * 2560;
    for (int n = n0 + tid * 4; n < n0 + 2560; n += 1024) {
        f32x4 s = (f32x4){0.f, 0.f, 0.f, 0.f};
        #pragma unroll
        for (int kc = 0; kc < 8; kc++)
            s += *(const f32x4*)(XG_part + (size_t)kc * BN + (size_t)b * NPAD + n);
        *(f32x4*)(XG + (size_t)b * NPAD + n) = s;
        #pragma unroll
        for (int j = 0; j < 4; j++) {
            int nn = n + j;
            if (nn < N_SZ) mx = fmaxf(mx, c1 * s[j] - c2 * G2[nn]);
        }
    }
    #pragma unroll
    for (int o = 32; o > 0; o >>= 1) mx = fmaxf(mx, __shfl_xor(mx, o));
    if ((tid & 63) == 0) wred[tid >> 6] = mx;
    __syncthreads();
    if (tid == 0) {
        mx = fmaxf(fmaxf(wred[0], wred[1]), fmaxf(wred[2], wred[3]));
        atomicMax(&Mkey[b], fkey_enc(mx));
    }
}

// ---------------- expk: P = bf16(exp(s - m)), L[b] += partial sum ----------
__global__ __launch_bounds__(256) void expk(
        const float* __restrict__ XG, const float* __restrict__ G2,
        const float* __restrict__ tarr, const unsigned* __restrict__ Mkey,
        unsigned short* __restrict__ P, float* __restrict__ L)
{
    const int b  = blockIdx.x >> 3;
    const int ch = blockIdx.x & 7;
    const int tid = threadIdx.x;
    float tt  = tarr[b] / 999.0f;
    float sig = 1.0f - tt;
    float inv = 1.0f / (sig * sig);
    float c1 = tt * inv, c2 = 0.5f * tt * tt * inv;
    float m = fkey_dec(Mkey[b]);
    const float* xg = XG + (size_t)b * NPAD;
    unsigned short* prow = P + (size_t)b * NPAD;
    __shared__ float wred[4];

    float sum = 0.f;
    int n0 = ch * 2560;
    for (int n = n0 + tid; n < n0 + 2560; n += 256) {
        float p = 0.f;
        if (n < N_SZ) { p = expf(c1 * xg[n] - c2 * G2[n] - m); sum += p; }
        prow[n] = f2bf(p);            // pad region -> exact 0
    }
    #pragma unroll
    for (int o = 32; o > 0; o >>= 1) sum += __shfl_xor(sum, o);
    if ((tid & 63) == 0) wred[tid >> 6] = sum;
    __syncthreads();
    if (tid == 0) atomicAdd(&L[b], wred[0] + wred[1] + wred[2] + wred[3]);
}

// ---------------- drift: Dacc_part[kc][b][d] = partial P.gt (plain stores) -
// grid = 24 d-tiles * 40 K-chunks = 960 blocks; K-chunk 512 (16 steps of 32).
// Same 1-barrier double-buffered pipeline as scores.
__global__ __launch_bounds__(256) void drift_kernel(
        const float* __restrict__ gt,
        const unsigned short* __restrict__ P,
        float* __restrict__ Dacc_part)
{
    __shared__ __align__(16) unsigned short Pt[2 * 128 * 32];       // 16 KB
    __shared__ __align__(16) unsigned short Gt[2 * 128 * 40];       // 20 KB ([d][k], 80B rows)

    const int tid = threadIdx.x;
    const int nt = blockIdx.x % 24;
    const int kc = blockIdx.x / 24;
    const int dbase = nt * 128;

    const int lane = tid & 63;
    const int wave = tid >> 6;
    const int mh = wave & 1;
    const int dh = wave >> 1;
    const int lm = lane & 15;
    const int qd = lane >> 4;

    // G staging map: thread -> (d-group of 4 cols, k-group of 4 rows)
    const int dg = tid & 31;
    const int kq = tid >> 5;

    // P staging (global_load_lds, swizzled source)
    int psrc[2], pdst[2];
    #pragma unroll
    for (int i = 0; i < 2; i++) {
        int o = (i * 256 + tid) * 16;
        int r = o >> 6;
        int j = (o >> 4) & 3;
        pdst[i] = o;
        psrc[i] = r * NPAD + kc * 512 + swz(r, j) * 8;
    }

    f32x4 acc[4][4];
    #pragma unroll
    for (int i = 0; i < 4; i++)
        #pragma unroll
        for (int j = 0; j < 4; j++)
            acc[i][j] = (f32x4){0.f, 0.f, 0.f, 0.f};

    // ---- prologue: stage step 0 into buffer 0 ----
    {
        #pragma unroll
        for (int i = 0; i < 2; i++)
            gl_lds16(P + psrc[i], (char*)Pt + pdst[i]);
        f32x4 row[4];
        #pragma unroll
        for (int i = 0; i < 4; i++) {
            int kg = kc * 512 + kq * 4 + i;
            if (kg > N_SZ - 1) kg = N_SZ - 1;
            row[i] = *(const f32x4*)(gt + (size_t)kg * D_SZ + dbase + dg * 4);
        }
        #pragma unroll
        for (int j = 0; j < 4; j++) {
            unsigned u01 = (unsigned)f2bf(row[0][j]) | ((unsigned)f2bf(row[1][j]) << 16);
            unsigned u23 = (unsigned)f2bf(row[2][j]) | ((unsigned)f2bf(row[3][j]) << 16);
            uint2v pk = (uint2v){u01, u23};
            __builtin_memcpy((char*)Gt + (size_t)(dg * 4 + j) * 80 + kq * 8, &pk, 8);
        }
        __syncthreads();
    }

    for (int s = 0; s < 16; s++) {
        const int cur = s & 1;
        const int nxt = cur ^ 1;

        f32x4 row[4];
        if (s < 15) {
            // prefetch P step s+1 into buf nxt
            #pragma unroll
            for (int i = 0; i < 2; i++)
                gl_lds16(P + psrc[i] + (s + 1) * 32, (char*)Pt + nxt * 8192 + pdst[i]);
            // G rows for step s+1
            int kb = kc * 512 + (s + 1) * 32;
            #pragma unroll
            for (int i = 0; i < 4; i++) {
                int kg = kb + kq * 4 + i;
                if (kg > N_SZ - 1) kg = N_SZ - 1;   // clamp; P=0 there
                row[i] = *(const f32x4*)(gt + (size_t)kg * D_SZ + dbase + dg * 4);
            }
        }

        // MFMA phase on buffer cur
        {
            const int pb = cur * 4096;       // elems
            const int gbB = cur * 10240;     // bytes
            short8 af[4], bf8[4];
            #pragma unroll
            for (int mi = 0; mi < 4; mi++) {
                int r = mh * 64 + mi * 16 + lm;
                af[mi] = *(short8*)&Pt[pb + r * 32 + swz(r, qd) * 8];
            }
            #pragma unroll
            for (int ni = 0; ni < 4; ni++)
                bf8[ni] = *(short8*)((char*)Gt + gbB + (size_t)(dh * 64 + ni * 16 + lm) * 80 + qd * 16);
            #pragma unroll
            for (int mi = 0; mi < 4; mi++)
                #pragma unroll
                for (int ni = 0; ni < 4; ni++)
                    acc[mi][ni] = __builtin_amdgcn_mfma_f32_16x16x32_bf16(af[mi], bf8[ni], acc[mi][ni], 0, 0, 0);
        }

        // convert + stage G step s+1 into buf nxt
        if (s < 15) {
            #pragma unroll
            for (int j = 0; j < 4; j++) {
                unsigned u01 = (unsigned)f2bf(row[0][j]) | ((unsigned)f2bf(row[1][j]) << 16);
                unsigned u23 = (unsigned)f2bf(row[2][j]) | ((unsigned)f2bf(row[3][j]) << 16);
                uint2v pk = (uint2v){u01, u23};
                __builtin_memcpy((char*)Gt + nxt * 10240 + (size_t)(dg * 4 + j) * 80 + kq * 8, &pk, 8);
            }
        }
        __syncthreads();
    }

    float* Dp = Dacc_part + (size_t)kc * BD;
    #pragma unroll
    for (int mi = 0; mi < 4; mi++)
        #pragma unroll
        for (int ni = 0; ni < 4; ni++) {
            int d = dbase + dh * 64 + ni * 16 + lm;
            #pragma unroll
            for (int i = 0; i < 4; i++) {
                int m = mh * 64 + mi * 16 + qd * 4 + i;
                Dp[(size_t)m * D_SZ + d] = acc[mi][ni][i];
            }
        }
}

// ---------------- epilogue: out = (sum_kc Dacc_part / L - x)/sig ----------
__global__ __launch_bounds__(256) void epilogue_kernel(
        const float* __restrict__ Dacc_part, const float* __restrict__ L,
        const float* __restrict__ x, const float* __restrict__ tarr,
        float* __restrict__ out)
{
    int i = (blockIdx.x * 256 + threadIdx.x) * 4;   // grid 384: covers BD
    int b = i / D_SZ;
    f32x4 s = (f32x4){0.f, 0.f, 0.f, 0.f};
    #pragma unroll
    for (int kc = 0; kc < 40; kc++)
        s += *(const f32x4*)(Dacc_part + (size_t)kc * BD + i);
    float tt = tarr[b] / 999.0f;
    float sig = 1.0f - tt;
    float invL = 1.0f / L[b];
    f32x4 xv = *(const f32x4*)(x + i);
    f32x4 o;
    #pragma unroll
    for (int j = 0; j < 4; j++) o[j] = (s[j] * invL - xv[j]) / sig;
    *(f32x4*)(out + i) = o;
}

extern "C" void kernel_launch(void* const* d_in, const int* in_sizes, int n_in,
                              void* d_out, int out_size, void* d_ws, size_t ws_size,
                              hipStream_t stream)
{
    const float* xt = (const float*)d_in[0];   // [128,3,32,32]
    const float* t  = (const float*)d_in[1];   // [128]
    const float* gt = (const float*)d_in[2];   // [20000,3,32,32]
    float* out = (float*)d_out;

    char* ws = (char*)d_ws;
    float*          XG_part  = (float*)(ws + 0);            // 8*BN*4   = 83886080
    float*          XG       = (float*)(ws + 83886080);     // BN*4     = 10485760
    float*          Dacc_part= (float*)(ws + 94371840);     // 40*BD*4  = 62914560
    float*          G2       = (float*)(ws + 157286400);    // 81920  } zeroed
    unsigned*       Mkey     = (unsigned*)(ws + 157368320); //   512  } contiguous
    float*          L        = (float*)(ws + 157368832);    //   512  } 20736 f32
    unsigned short* Xhi      = (unsigned short*)(ws + 157369344); // 786432
    unsigned short* Xlo      = (unsigned short*)(ws + 158155776); // 786432
    unsigned short* P        = (unsigned short*)(ws + 158942208); // 5242880
    // total ~164 MB

    zero_small    <<<   81, 256, 0, stream>>>(G2);           // G2+Mkey+L
    prep_x        <<< 1536, 256, 0, stream>>>(xt, Xhi, Xlo);
    scores_kernel <<< 2504, 256, 0, stream>>>(gt, Xhi, Xlo, XG_part, G2);
    maxk          <<< 1024, 256, 0, stream>>>(XG_part, G2, t, Mkey, XG);
    expk          <<< 1024, 256, 0, stream>>>(XG, G2, t, Mkey, P, L);
    drift_kernel  <<<  960, 256, 0, stream>>>(gt, P, Dacc_part);
    epilogue_kernel<<< 384, 256, 0, stream>>>(Dacc_part, L, xt, t, out);
}